// Round 2
// baseline (464.455 us; speedup 1.0000x reference)
//
#include <hip/hip_runtime.h>

// Fused: h = relu(x @ fc1_w.T + b); TT exp-machine contraction; fc2.
// B=16384, D_IN=4096, D=10, R=2, C=10.
//
// R2 changes vs R1:
//  - NROWS 32->16, KSPLIT 8->32, block 256->512, grid 512->1024
//    => 4 blocks/CU, 32 waves/CU (was 8 waves/CU) for latency hiding.
//  - Macro-iteration consumes a FULL 64B x line per lane (4 adjacent float4
//    loads, 16 elements) before advancing => no cross-iteration line reuse
//    => kills the +30% HBM refetch seen in R1 (FETCH 350MB vs 268MB ideal).
//  - LDS pad 10->11 to break bank aliasing on the accumulator writes.

#define NROWS   16
#define KSPLIT  32
#define CHUNK   128    // 4096 / KSPLIT floats per thread
#define DIN     4096
#define PAD     11

__global__ __launch_bounds__(512, 8) void fused_linexp_kernel(
    const float* __restrict__ x,           // [16384, 4096]
    const float* __restrict__ fc1_w,       // [10, 4096]
    const float* __restrict__ fc1_b,       // [10]
    const float* __restrict__ core_first,  // [1, 2, 2]  -> cf[m*2 + r]
    const float* __restrict__ cores_mid,   // [8, 2, 2, 2] -> cm[k*8 + r*4 + m*2 + r']
    const float* __restrict__ core_last,   // [2, 2, 10] -> cl[(r*2+m)*10 + c]
    const float* __restrict__ fc2_w,       // [10, 10]
    const float* __restrict__ fc2_b,       // [10]
    float* __restrict__ out)               // [16384, 10]
{
    __shared__ float lds_acc[KSPLIT][NROWS][PAD];
    __shared__ float lds_h[NROWS][PAD];

    const int t     = threadIdx.x;
    const int lrow  = t & (NROWS - 1);
    const int chunk = t >> 4;                 // 0..31
    const int grow  = blockIdx.x * NROWS + lrow;

    const float* xp = x + (size_t)grow * DIN + chunk * CHUNK;
    const float* wp = fc1_w + chunk * CHUNK;

    float acc[10];
#pragma unroll
    for (int j = 0; j < 10; ++j) acc[j] = 0.0f;

    // 8 macro-iterations; each consumes one full 64B x line per lane.
#pragma unroll 1
    for (int m = 0; m < CHUNK / 16; ++m) {
        float4 xv[4];
#pragma unroll
        for (int s = 0; s < 4; ++s)
            xv[s] = *reinterpret_cast<const float4*>(xp + m * 16 + s * 4);
#pragma unroll
        for (int j = 0; j < 10; ++j) {
            float a = acc[j];
#pragma unroll
            for (int s = 0; s < 4; ++s) {
                const float4 wv =
                    *reinterpret_cast<const float4*>(wp + (size_t)j * DIN + m * 16 + s * 4);
                a = fmaf(xv[s].x, wv.x, a);
                a = fmaf(xv[s].y, wv.y, a);
                a = fmaf(xv[s].z, wv.z, a);
                a = fmaf(xv[s].w, wv.w, a);
            }
            acc[j] = a;
        }
    }

#pragma unroll
    for (int j = 0; j < 10; ++j) lds_acc[chunk][lrow][j] = acc[j];
    __syncthreads();

    // 32-way chunk reduction + bias + relu: 160 (row,j) items.
    if (t < NROWS * 10) {
        const int row = t / 10;
        const int j   = t - row * 10;
        float s = 0.0f;
#pragma unroll
        for (int c = 0; c < KSPLIT; ++c) s += lds_acc[c][row][j];
        s += fc1_b[j];
        lds_h[row][j] = s > 0.0f ? s : 0.0f;
    }
    __syncthreads();

    // Epilogue: one thread per row runs the TT chain + fc2 (~120 FLOP).
    if (t < NROWS) {
        float h[10];
#pragma unroll
        for (int j = 0; j < 10; ++j) h[j] = lds_h[t][j];

        // v = cf[0,:] + h0 * cf[1,:]   (cf[m*2 + r])
        float v0 = core_first[0] + h[0] * core_first[2];
        float v1 = core_first[1] + h[0] * core_first[3];

#pragma unroll
        for (int k = 0; k < 8; ++k) {
            const float* M = cores_mid + k * 8;  // M[r*4 + m*2 + r']
            const float hk = h[k + 1];
            const float n0 = fmaf(hk, fmaf(v0, M[2], v1 * M[6]), fmaf(v0, M[0], v1 * M[4]));
            const float n1 = fmaf(hk, fmaf(v0, M[3], v1 * M[7]), fmaf(v0, M[1], v1 * M[5]));
            v0 = n0; v1 = n1;
        }

        float vc[10];
#pragma unroll
        for (int c = 0; c < 10; ++c) {
            // cl[(r*2+m)*10 + c]
            vc[c] = fmaf(h[9], fmaf(v0, core_last[10 + c], v1 * core_last[30 + c]),
                         fmaf(v0, core_last[c], v1 * core_last[20 + c]));
        }

        float* op = out + (size_t)(blockIdx.x * NROWS + t) * 10;
#pragma unroll
        for (int n = 0; n < 10; ++n) {
            float o = fc2_b[n];
#pragma unroll
            for (int c = 0; c < 10; ++c) o = fmaf(vc[c], fc2_w[n * 10 + c], o);
            op[n] = o;
        }
    }
}

extern "C" void kernel_launch(void* const* d_in, const int* in_sizes, int n_in,
                              void* d_out, int out_size, void* d_ws, size_t ws_size,
                              hipStream_t stream) {
    const float* x          = (const float*)d_in[0];
    const float* fc1_w      = (const float*)d_in[1];
    const float* fc1_b      = (const float*)d_in[2];
    const float* core_first = (const float*)d_in[3];
    const float* cores_mid  = (const float*)d_in[4];
    const float* core_last  = (const float*)d_in[5];
    const float* fc2_w      = (const float*)d_in[6];
    const float* fc2_b      = (const float*)d_in[7];
    float* out = (float*)d_out;

    dim3 grid(16384 / NROWS);  // 1024 blocks -> 4 blocks/CU, 32 waves/CU
    dim3 block(512);
    fused_linexp_kernel<<<grid, block, 0, stream>>>(
        x, fc1_w, fc1_b, core_first, cores_mid, core_last, fc2_w, fc2_b, out);
}

// Round 4
// 411.809 us; speedup vs baseline: 1.1278x; 1.1278x over previous
//
#include <hip/hip_runtime.h>

// Fused: h = relu(x @ fc1_w.T + b); TT exp-machine contraction; fc2.
// B=16384, D_IN=4096, D=10, R=2, C=10.
//
// R3 changes vs R2 (resubmitted in R4 — R3 bench never ran, broker timeout):
//  - REMOVED the second __launch_bounds__ arg. R2's (512,8) capped VGPR at 64,
//    compiler allocated 32 and spilled xv[]/acc[] to scratch -> 163 MB of
//    HBM write traffic (rocprof WRITE_SIZE) and the 203us regression.
//  - Occupancy now comes from grid shape: NROWS=8, KSPLIT=32, block=256
//    -> grid 2048 = 8 blocks/CU = 32 waves/CU (R1 had only 2 blocks/CU).
//  - Keeps R2's full-line macro-iteration (lane consumes its whole 64B x line
//    in 4 adjacent loads) so no cross-iteration line refetch (R1: +30% FETCH).
//  - w is broadcast: 8 lanes share each w address -> w L2 traffic ~330 MB
//    (~10us at L2 BW), negligible next to the 268 MB x HBM stream.

#define NROWS   8
#define KSPLIT  32
#define CHUNK   128    // 4096 / KSPLIT floats per thread
#define DIN     4096
#define PAD     11

__global__ __launch_bounds__(256) void fused_linexp_kernel(
    const float* __restrict__ x,           // [16384, 4096]
    const float* __restrict__ fc1_w,       // [10, 4096]
    const float* __restrict__ fc1_b,       // [10]
    const float* __restrict__ core_first,  // [1, 2, 2]  -> cf[m*2 + r]
    const float* __restrict__ cores_mid,   // [8, 2, 2, 2] -> cm[k*8 + r*4 + m*2 + r']
    const float* __restrict__ core_last,   // [2, 2, 10] -> cl[(r*2+m)*10 + c]
    const float* __restrict__ fc2_w,       // [10, 10]
    const float* __restrict__ fc2_b,       // [10]
    float* __restrict__ out)               // [16384, 10]
{
    __shared__ float lds_acc[KSPLIT][NROWS][PAD];
    __shared__ float lds_h[NROWS][PAD];

    const int t     = threadIdx.x;
    const int lrow  = t & (NROWS - 1);
    const int chunk = t >> 3;                 // 0..31
    const int grow  = blockIdx.x * NROWS + lrow;

    const float* xp = x + (size_t)grow * DIN + chunk * CHUNK;
    const float* wp = fc1_w + chunk * CHUNK;

    float acc[10];
#pragma unroll
    for (int j = 0; j < 10; ++j) acc[j] = 0.0f;

    // 8 macro-iterations; each consumes one full 64B x line per lane.
#pragma unroll 1
    for (int m = 0; m < CHUNK / 16; ++m) {
        float4 xv[4];
#pragma unroll
        for (int s = 0; s < 4; ++s)
            xv[s] = *reinterpret_cast<const float4*>(xp + m * 16 + s * 4);
#pragma unroll
        for (int j = 0; j < 10; ++j) {
            float a = acc[j];
#pragma unroll
            for (int s = 0; s < 4; ++s) {
                const float4 wv =
                    *reinterpret_cast<const float4*>(wp + (size_t)j * DIN + m * 16 + s * 4);
                a = fmaf(xv[s].x, wv.x, a);
                a = fmaf(xv[s].y, wv.y, a);
                a = fmaf(xv[s].z, wv.z, a);
                a = fmaf(xv[s].w, wv.w, a);
            }
            acc[j] = a;
        }
    }

#pragma unroll
    for (int j = 0; j < 10; ++j) lds_acc[chunk][lrow][j] = acc[j];
    __syncthreads();

    // 32-way chunk reduction + bias + relu: 80 (row,j) items.
    if (t < NROWS * 10) {
        const int row = t / 10;
        const int j   = t - row * 10;
        float s = 0.0f;
#pragma unroll
        for (int c = 0; c < KSPLIT; ++c) s += lds_acc[c][row][j];
        s += fc1_b[j];
        lds_h[row][j] = s > 0.0f ? s : 0.0f;
    }
    __syncthreads();

    // Epilogue: one thread per row runs the TT chain + fc2 (~120 FLOP).
    if (t < NROWS) {
        float h[10];
#pragma unroll
        for (int j = 0; j < 10; ++j) h[j] = lds_h[t][j];

        // v = cf[0,:] + h0 * cf[1,:]   (cf[m*2 + r])
        float v0 = core_first[0] + h[0] * core_first[2];
        float v1 = core_first[1] + h[0] * core_first[3];

#pragma unroll
        for (int k = 0; k < 8; ++k) {
            const float* M = cores_mid + k * 8;  // M[r*4 + m*2 + r']
            const float hk = h[k + 1];
            const float n0 = fmaf(hk, fmaf(v0, M[2], v1 * M[6]), fmaf(v0, M[0], v1 * M[4]));
            const float n1 = fmaf(hk, fmaf(v0, M[3], v1 * M[7]), fmaf(v0, M[1], v1 * M[5]));
            v0 = n0; v1 = n1;
        }

        float vc[10];
#pragma unroll
        for (int c = 0; c < 10; ++c) {
            // cl[(r*2+m)*10 + c]
            vc[c] = fmaf(h[9], fmaf(v0, core_last[10 + c], v1 * core_last[30 + c]),
                         fmaf(v0, core_last[c], v1 * core_last[20 + c]));
        }

        float* op = out + (size_t)(blockIdx.x * NROWS + t) * 10;
#pragma unroll
        for (int n = 0; n < 10; ++n) {
            float o = fc2_b[n];
#pragma unroll
            for (int c = 0; c < 10; ++c) o = fmaf(vc[c], fc2_w[n * 10 + c], o);
            op[n] = o;
        }
    }
}

extern "C" void kernel_launch(void* const* d_in, const int* in_sizes, int n_in,
                              void* d_out, int out_size, void* d_ws, size_t ws_size,
                              hipStream_t stream) {
    const float* x          = (const float*)d_in[0];
    const float* fc1_w      = (const float*)d_in[1];
    const float* fc1_b      = (const float*)d_in[2];
    const float* core_first = (const float*)d_in[3];
    const float* cores_mid  = (const float*)d_in[4];
    const float* core_last  = (const float*)d_in[5];
    const float* fc2_w      = (const float*)d_in[6];
    const float* fc2_b      = (const float*)d_in[7];
    float* out = (float*)d_out;

    dim3 grid(16384 / NROWS);  // 2048 blocks -> 8 blocks/CU, 32 waves/CU
    dim3 block(256);
    fused_linexp_kernel<<<grid, block, 0, stream>>>(
        x, fc1_w, fc1_b, core_first, cores_mid, core_last, fc2_w, fc2_b, out);
}

// Round 8
// 385.649 us; speedup vs baseline: 1.2043x; 1.0678x over previous
//
#include <hip/hip_runtime.h>

// Fused: h = relu(x @ fc1_w.T + b); TT exp-machine contraction; fc2.
// B=16384, D_IN=4096, D=10, R=2, C=10.
//
// R5 restructure vs R3 (inferred kernel ~150us, request-rate-limited);
// resubmitted unchanged (R6-R8) — broker timeouts, never measured.
//  R3 mapped lane->row: every x load instr touched 64 DISTINCT cache lines
//  (one per lane) and every w load 8 distinct lines -> ~38M line-requests
//  through the TA at ~1/cy/CU ~= 61us+ address floor. VALUBusy was low, BW
//  stuck at ~2 TB/s.
//  R5 maps lanes ACROSS K: wave = TM=4 rows x full K in 16 slices of 256
//  floats; lane l loads float4 at col 4l -> every x load instruction is one
//  contiguous 1KB segment (16 lines, minimal requests), each line consumed
//  exactly once. w loads equally coalesced and L1-hot (w panel is 160KB,
//  reread per wave from L1 -> ~650MB aggregate L1 traffic, negligible).
//  Accumulate acc[4][10]/lane; 6-step __shfl_xor butterfly (240 shfl+add)
//  reduces over the wave; lanes 0..3 then run the tiny TT chain + fc2.
//  NO LDS, no __syncthreads, double-buffered x prefetch.
//  Grid 1024 x 256 -> 4 blocks/CU, 16 waves/CU; ~100 VGPR, no spills.

#define TM      4
#define DIN     4096
#define SLICE   256            // floats per wave-slice (64 lanes * 4)
#define NSLICE  (DIN / SLICE)  // 16

__global__ __launch_bounds__(256) void fused_linexp_kernel(
    const float* __restrict__ x,           // [16384, 4096]
    const float* __restrict__ fc1_w,       // [10, 4096]
    const float* __restrict__ fc1_b,       // [10]
    const float* __restrict__ core_first,  // [1, 2, 2]  -> cf[m*2 + r]
    const float* __restrict__ cores_mid,   // [8, 2, 2, 2] -> cm[k*8 + r*4 + m*2 + r']
    const float* __restrict__ core_last,   // [2, 2, 10] -> cl[(r*2+m)*10 + c]
    const float* __restrict__ fc2_w,       // [10, 10]
    const float* __restrict__ fc2_b,       // [10]
    float* __restrict__ out)               // [16384, 10]
{
    const int t    = threadIdx.x;
    const int lane = t & 63;
    const int wid  = t >> 6;                              // 0..3
    const int rowbase = (blockIdx.x * 4 + wid) * TM;

    const float* xp = x + (size_t)rowbase * DIN + lane * 4;
    const float* wq = fc1_w + lane * 4;

    float acc[TM][10];
#pragma unroll
    for (int r = 0; r < TM; ++r)
#pragma unroll
        for (int j = 0; j < 10; ++j) acc[r][j] = 0.0f;

    float4 xc[TM], xn[TM];
#pragma unroll
    for (int r = 0; r < TM; ++r)
        xc[r] = *reinterpret_cast<const float4*>(xp + (size_t)r * DIN);

#pragma unroll 1
    for (int s = 0; s < NSLICE; ++s) {
        if (s + 1 < NSLICE) {
#pragma unroll
            for (int r = 0; r < TM; ++r)
                xn[r] = *reinterpret_cast<const float4*>(
                    xp + (size_t)r * DIN + (s + 1) * SLICE);
        }
        const float* wqs = wq + s * SLICE;
#pragma unroll
        for (int j = 0; j < 10; ++j) {
            const float4 wv = *reinterpret_cast<const float4*>(wqs + (size_t)j * DIN);
#pragma unroll
            for (int r = 0; r < TM; ++r) {
                float a = acc[r][j];
                a = fmaf(xc[r].x, wv.x, a);
                a = fmaf(xc[r].y, wv.y, a);
                a = fmaf(xc[r].z, wv.z, a);
                a = fmaf(xc[r].w, wv.w, a);
                acc[r][j] = a;
            }
        }
#pragma unroll
        for (int r = 0; r < TM; ++r) xc[r] = xn[r];
    }

    // Wave-wide butterfly reduction: every lane ends with the full K-sum.
#pragma unroll
    for (int m = 1; m < 64; m <<= 1) {
#pragma unroll
        for (int r = 0; r < TM; ++r)
#pragma unroll
            for (int j = 0; j < 10; ++j)
                acc[r][j] += __shfl_xor(acc[r][j], m, 64);
    }

    // Lanes 0..3: TT chain + fc2 for row (rowbase + lane).
    if (lane < TM) {
        float h[10];
#pragma unroll
        for (int j = 0; j < 10; ++j) {
            const float s = acc[lane][j] + fc1_b[j];
            h[j] = s > 0.0f ? s : 0.0f;
        }

        // v = cf[0,:] + h0 * cf[1,:]   (cf[m*2 + r])
        float v0 = core_first[0] + h[0] * core_first[2];
        float v1 = core_first[1] + h[0] * core_first[3];

#pragma unroll
        for (int k = 0; k < 8; ++k) {
            const float* M = cores_mid + k * 8;  // M[r*4 + m*2 + r']
            const float hk = h[k + 1];
            const float n0 = fmaf(hk, fmaf(v0, M[2], v1 * M[6]), fmaf(v0, M[0], v1 * M[4]));
            const float n1 = fmaf(hk, fmaf(v0, M[3], v1 * M[7]), fmaf(v0, M[1], v1 * M[5]));
            v0 = n0; v1 = n1;
        }

        float vc[10];
#pragma unroll
        for (int c = 0; c < 10; ++c) {
            // cl[(r*2+m)*10 + c]
            vc[c] = fmaf(h[9], fmaf(v0, core_last[10 + c], v1 * core_last[30 + c]),
                         fmaf(v0, core_last[c], v1 * core_last[20 + c]));
        }

        float* op = out + (size_t)(rowbase + lane) * 10;
#pragma unroll
        for (int n = 0; n < 10; ++n) {
            float o = fc2_b[n];
#pragma unroll
            for (int c = 0; c < 10; ++c) o = fmaf(vc[c], fc2_w[n * 10 + c], o);
            op[n] = o;
        }
    }
}

extern "C" void kernel_launch(void* const* d_in, const int* in_sizes, int n_in,
                              void* d_out, int out_size, void* d_ws, size_t ws_size,
                              hipStream_t stream) {
    const float* x          = (const float*)d_in[0];
    const float* fc1_w      = (const float*)d_in[1];
    const float* fc1_b      = (const float*)d_in[2];
    const float* core_first = (const float*)d_in[3];
    const float* cores_mid  = (const float*)d_in[4];
    const float* core_last  = (const float*)d_in[5];
    const float* fc2_w      = (const float*)d_in[6];
    const float* fc2_b      = (const float*)d_in[7];
    float* out = (float*)d_out;

    // 16384 rows / (4 waves/block * TM=4 rows/wave) = 1024 blocks
    // -> 4 blocks/CU, 16 waves/CU.
    dim3 grid(16384 / (4 * TM));
    dim3 block(256);
    fused_linexp_kernel<<<grid, block, 0, stream>>>(
        x, fc1_w, fc1_b, core_first, cores_mid, core_last, fc2_w, fc2_b, out);
}